// Round 2
// baseline (785.106 us; speedup 1.0000x reference)
//
#include <hip/hip_runtime.h>
#include <hip/hip_bf16.h>
#include <cstdint>

#define N_SAMP 8192
#define IN_DIM 1024
#define HID    2048
#define NE     4

typedef __attribute__((ext_vector_type(8))) __bf16 bf16x8;
typedef __attribute__((ext_vector_type(4))) float  f32x4;

__device__ __forceinline__ unsigned short f2b(float f) {
    unsigned u = __float_as_uint(f);
    u += 0x7fff + ((u >> 16) & 1);          // RNE, finite inputs only
    return (unsigned short)(u >> 16);
}
__device__ __forceinline__ float b2f(unsigned short s) {
    return __uint_as_float(((unsigned)s) << 16);
}

// async global->LDS, 16B per lane; LDS dest is wave-uniform base (+lane*16 by HW)
__device__ __forceinline__ void gll16(const void* g, void* l) {
    __builtin_amdgcn_global_load_lds(
        (const __attribute__((address_space(1))) void*)g,
        (__attribute__((address_space(3))) void*)l,
        16, 0, 0);
}

// ---------------- f32 -> bf16 elementwise ----------------
__global__ void conv_bf16(const float* __restrict__ s, unsigned short* __restrict__ d, int n) {
    int i = (blockIdx.x * blockDim.x + threadIdx.x) * 4;
    if (i >= n) return;
    float4 v = *(const float4*)&s[i];
    ushort4 o;
    o.x = f2b(v.x); o.y = f2b(v.y); o.z = f2b(v.z); o.w = f2b(v.w);
    *(ushort4*)&d[i] = o;
}

// ---------------- transpose + convert: src [K][M] f32 -> dst [M][K] bf16 ----------------
__global__ void transpose_conv(const float* __restrict__ src, unsigned short* __restrict__ dst,
                               int K, int M) {
    __shared__ float tile[64][65];
    const int k0 = blockIdx.x * 64, m0 = blockIdx.y * 64;
    const int t  = threadIdx.x;
    const int tc = t & 15, tr = t >> 4;     // tc: 4-col group, tr: row
    const float* s = src + (size_t)k0 * M + m0;
    #pragma unroll
    for (int r = tr; r < 64; r += 16) {
        float4 v = *(const float4*)&s[(size_t)r * M + tc * 4];
        tile[r][tc * 4 + 0] = v.x; tile[r][tc * 4 + 1] = v.y;
        tile[r][tc * 4 + 2] = v.z; tile[r][tc * 4 + 3] = v.w;
    }
    __syncthreads();
    unsigned short* d = dst + (size_t)m0 * K + k0;
    #pragma unroll
    for (int r = tr; r < 64; r += 16) {
        ushort4 o;
        o.x = f2b(tile[tc * 4 + 0][r]); o.y = f2b(tile[tc * 4 + 1][r]);
        o.z = f2b(tile[tc * 4 + 2][r]); o.w = f2b(tile[tc * 4 + 3][r]);
        *(ushort4*)&d[(size_t)r * K + tc * 4] = o;
    }
}

// ---------------- router: fp32 logits, softmax, first-max argmax, reg_loss ----------------
__global__ void router_kernel(const float* __restrict__ bb, const int* __restrict__ task,
                              const float* __restrict__ temb, const float* __restrict__ rm,
                              float* __restrict__ gval, int* __restrict__ gidx,
                              float* __restrict__ regout) {
    const int t = threadIdx.x, wave = t >> 6, lane = t & 63;
    const int n = blockIdx.x * 4 + wave;
    const int tk = task[n];
    float a0 = 0.f, a1 = 0.f, a2 = 0.f, a3 = 0.f;
    for (int i = lane; i < IN_DIM + 100; i += 64) {
        float x = (i < IN_DIM) ? bb[(size_t)n * IN_DIM + i] : temb[tk * 100 + (i - IN_DIM)];
        float4 r = *(const float4*)&rm[i * 4];
        a0 += x * r.x; a1 += x * r.y; a2 += x * r.z; a3 += x * r.w;
    }
    #pragma unroll
    for (int o = 32; o; o >>= 1) {
        a0 += __shfl_xor(a0, o); a1 += __shfl_xor(a1, o);
        a2 += __shfl_xor(a2, o); a3 += __shfl_xor(a3, o);
    }
    if (lane == 0) {
        float l[4] = {a0, a1, a2, a3};
        float mx = fmaxf(fmaxf(l[0], l[1]), fmaxf(l[2], l[3]));
        float ex[4], s = 0.f;
        #pragma unroll
        for (int j = 0; j < 4; j++) { ex[j] = expf(l[j] - mx); s += ex[j]; }
        int bi = 0; float bw = ex[0];
        #pragma unroll
        for (int j = 1; j < 4; j++) if (ex[j] > bw) { bw = ex[j]; bi = j; }
        float g = bw / s;
        gval[n] = g;
        gidx[n] = bi;
        regout[n] = -0.0025f * (logf(g + 1e-6f) + 3.0f * logf(1e-6f));
    }
}

// ---------------- bf16 MFMA GEMM: C[n][m] = relu(A[n,:] . BT[m,:] + bias[m]) ----------
// A: [N][K] bf16, BT: [M][K] bf16, 128x128 tile, BK=32, 4 waves
__global__ __launch_bounds__(256) void gemm_bias_relu(
    const unsigned short* __restrict__ A, const unsigned short* __restrict__ BT,
    const float* __restrict__ bias, unsigned short* __restrict__ C,
    int K, int M) {
    __shared__ __attribute__((aligned(16))) unsigned short lA[128 * 32];
    __shared__ __attribute__((aligned(16))) unsigned short lB[128 * 32];
    const int t = threadIdx.x;
    const int m0 = blockIdx.x * 128;
    const int n0 = blockIdx.y * 128;
    const unsigned short* Ab = A + (size_t)n0 * K;
    const unsigned short* Bb = BT + (size_t)m0 * K;
    const int wave = t >> 6, lane = t & 63;
    const int wr = wave >> 1, wc = wave & 1;
    const int lrow = lane & 15, kg = lane >> 4;

    // staging: chunk c covers 16B = row c>>2, 8-elem group c&3 of a [128][32] tile
    const int c0 = t, c1 = t + 256;
    const int r0 = c0 >> 2, o0 = (c0 & 3) * 8;
    const int r1 = c1 >> 2, o1 = (c1 & 3) * 8;
    unsigned short* lA0 = &lA[(size_t)wave * 512];
    unsigned short* lA1 = &lA[2048 + (size_t)wave * 512];
    unsigned short* lB0 = &lB[(size_t)wave * 512];
    unsigned short* lB1 = &lB[2048 + (size_t)wave * 512];

    f32x4 acc[4][4];
    #pragma unroll
    for (int i = 0; i < 4; i++)
        #pragma unroll
        for (int j = 0; j < 4; j++) acc[i][j] = (f32x4){0.f, 0.f, 0.f, 0.f};

    const int nk = K >> 5;
    for (int kt = 0; kt < nk; ++kt) {
        const unsigned short* Ak = Ab + kt * 32;
        const unsigned short* Bk = Bb + kt * 32;
        gll16(Ak + (size_t)r0 * K + o0, lA0);
        gll16(Ak + (size_t)r1 * K + o1, lA1);
        gll16(Bk + (size_t)r0 * K + o0, lB0);
        gll16(Bk + (size_t)r1 * K + o1, lB1);
        __syncthreads();
        bf16x8 af[4], bfr[4];
        #pragma unroll
        for (int i = 0; i < 4; i++)
            af[i] = *(const bf16x8*)&lA[(wr * 64 + i * 16 + lrow) * 32 + kg * 8];
        #pragma unroll
        for (int j = 0; j < 4; j++)
            bfr[j] = *(const bf16x8*)&lB[(wc * 64 + j * 16 + lrow) * 32 + kg * 8];
        #pragma unroll
        for (int i = 0; i < 4; i++)
            #pragma unroll
            for (int j = 0; j < 4; j++)
                acc[i][j] = __builtin_amdgcn_mfma_f32_16x16x32_bf16(af[i], bfr[j], acc[i][j], 0, 0, 0);
        __syncthreads();
    }

    // epilogue: C/D layout col=lane&15, row=(lane>>4)*4+q  (m89-verified)
    float bv[4];
    #pragma unroll
    for (int j = 0; j < 4; j++)
        bv[j] = bias[m0 + wc * 64 + j * 16 + lrow];
    unsigned short* Cb = C + (size_t)n0 * M + m0;
    #pragma unroll
    for (int i = 0; i < 4; i++) {
        #pragma unroll
        for (int j = 0; j < 4; j++) {
            const int oc = wc * 64 + j * 16 + lrow;
            #pragma unroll
            for (int q = 0; q < 4; q++) {
                const int sr = wr * 64 + i * 16 + kg * 4 + q;
                float x = acc[i][j][q] + bv[j];
                x = fmaxf(x, 0.f);
                Cb[(size_t)sr * M + oc] = f2b(x);
            }
        }
    }
}

// ---------------- Gram-Schmidt + gather: one wave per sample ----------------
__global__ void gs_kernel(const unsigned short* __restrict__ eo, const float* __restrict__ gval,
                          const int* __restrict__ gidx, float* __restrict__ dout) {
    const int t = threadIdx.x, wave = t >> 6, lane = t & 63;
    const int n = blockIdx.x * 4 + wave;
    const int idx = gidx[n];
    const float g = gval[n];

    float v[32], b0[32], b1[32], b2[32];

    auto loadv = [&](float* dst, int e) {
        const unsigned short* p = eo + ((size_t)e * N_SAMP + n) * HID + lane * 8;
        #pragma unroll
        for (int c = 0; c < 4; c++) {
            uint4 u = *(const uint4*)(p + c * 512);
            const unsigned short* us = (const unsigned short*)&u;
            #pragma unroll
            for (int j = 0; j < 8; j++) dst[c * 8 + j] = b2f(us[j]);
        }
    };
    auto wdot = [&](const float* x, const float* y) -> float {
        float s = 0.f;
        #pragma unroll
        for (int k = 0; k < 32; k++) s += x[k] * y[k];
        #pragma unroll
        for (int o = 32; o; o >>= 1) s += __shfl_xor(s, o);
        return s;
    };
    auto storev = [&](const float* b) {
        float* o = dout + (size_t)n * HID + lane * 8;
        #pragma unroll
        for (int c = 0; c < 4; c++) {
            float4 x0, x1;
            x0.x = g * b[c * 8 + 0]; x0.y = g * b[c * 8 + 1];
            x0.z = g * b[c * 8 + 2]; x0.w = g * b[c * 8 + 3];
            x1.x = g * b[c * 8 + 4]; x1.y = g * b[c * 8 + 5];
            x1.z = g * b[c * 8 + 6]; x1.w = g * b[c * 8 + 7];
            *(float4*)(o + c * 512) = x0;
            *(float4*)(o + c * 512 + 4) = x1;
        }
    };

    // b0
    loadv(v, 0);
    float inv = 1.f / sqrtf(wdot(v, v));
    #pragma unroll
    for (int k = 0; k < 32; k++) b0[k] = v[k] * inv;
    if (idx == 0) { storev(b0); return; }
    // b1 (classical GS: coefs from original v)
    loadv(v, 1);
    {
        float cc0 = wdot(v, b0);
        #pragma unroll
        for (int k = 0; k < 32; k++) v[k] -= cc0 * b0[k];
        inv = 1.f / sqrtf(wdot(v, v));
        #pragma unroll
        for (int k = 0; k < 32; k++) b1[k] = v[k] * inv;
    }
    if (idx == 1) { storev(b1); return; }
    // b2
    loadv(v, 2);
    {
        float cc0 = wdot(v, b0);
        float cc1 = wdot(v, b1);
        #pragma unroll
        for (int k = 0; k < 32; k++) v[k] -= cc0 * b0[k] + cc1 * b1[k];
        inv = 1.f / sqrtf(wdot(v, v));
        #pragma unroll
        for (int k = 0; k < 32; k++) b2[k] = v[k] * inv;
    }
    if (idx == 2) { storev(b2); return; }
    // b3
    loadv(v, 3);
    {
        float cc0 = wdot(v, b0);
        float cc1 = wdot(v, b1);
        float cc2 = wdot(v, b2);
        #pragma unroll
        for (int k = 0; k < 32; k++) v[k] -= cc0 * b0[k] + cc1 * b1[k] + cc2 * b2[k];
        inv = 1.f / sqrtf(wdot(v, v));
        #pragma unroll
        for (int k = 0; k < 32; k++) v[k] *= inv;
    }
    storev(v);
}

extern "C" void kernel_launch(void* const* d_in, const int* in_sizes, int n_in,
                              void* d_out, int out_size, void* d_ws, size_t ws_size,
                              hipStream_t stream) {
    const float* bb   = (const float*)d_in[0];
    const int*   task = (const int*)d_in[1];
    const float* temb = (const float*)d_in[2];
    const float* rm   = (const float*)d_in[3];
    const float* W1   = (const float*)d_in[4];
    const float* b1   = (const float*)d_in[5];
    const float* W2   = (const float*)d_in[6];
    const float* b2   = (const float*)d_in[7];
    float* out = (float*)d_out;

    // workspace layout (bytes) -- total ~188.1 MB
    char* ws = (char*)d_ws;
    unsigned short* obf = (unsigned short*)(ws + 0);           // 128 MB: [E][N][HID] bf16
    unsigned short* Abf = (unsigned short*)(ws + 134217728);   //  16 MB: [N][IN_DIM] bf16
    unsigned short* hbf = (unsigned short*)(ws + 150994944);   //  32 MB: [N][HID] bf16 (per-expert)
    unsigned short* W1T = (unsigned short*)(ws + 184549376);   //   4 MB: [HID][IN_DIM] bf16 (per-expert)
    unsigned short* W2T = (unsigned short*)(ws + 188743680);   //   8 MB: [HID][HID] bf16 (per-expert)
    float*          gv  = (float*)(ws + 197132288);            //  32 KB
    int*            gi  = (int*)(ws + 197165056);              //  32 KB

    conv_bf16<<<(N_SAMP * IN_DIM) / 1024, 256, 0, stream>>>(bb, Abf, N_SAMP * IN_DIM);
    router_kernel<<<N_SAMP / 4, 256, 0, stream>>>(bb, task, temb, rm, gv, gi,
                                                  out + (size_t)N_SAMP * HID);

    for (int e = 0; e < NE; ++e) {
        transpose_conv<<<dim3(IN_DIM / 64, HID / 64), 256, 0, stream>>>(
            W1 + (size_t)e * IN_DIM * HID, W1T, IN_DIM, HID);
        gemm_bias_relu<<<dim3(HID / 128, N_SAMP / 128), 256, 0, stream>>>(
            Abf, W1T, b1 + (size_t)e * HID, hbf, IN_DIM, HID);
        transpose_conv<<<dim3(HID / 64, HID / 64), 256, 0, stream>>>(
            W2 + (size_t)e * HID * HID, W2T, HID, HID);
        gemm_bias_relu<<<dim3(HID / 128, N_SAMP / 128), 256, 0, stream>>>(
            hbf, W2T, b2 + (size_t)e * HID, obf + (size_t)e * N_SAMP * HID, HID, HID);
    }

    gs_kernel<<<N_SAMP / 4, 256, 0, stream>>>(obf, gv, gi, out);
}

// Round 3
// 653.220 us; speedup vs baseline: 1.2019x; 1.2019x over previous
//
#include <hip/hip_runtime.h>
#include <hip/hip_bf16.h>
#include <cstdint>

#define N_SAMP 8192
#define IN_DIM 1024
#define HID    2048
#define NE     4

typedef __attribute__((ext_vector_type(8))) __bf16 bf16x8;
typedef __attribute__((ext_vector_type(4))) float  f32x4;

__device__ __forceinline__ unsigned short f2b(float f) {
    unsigned u = __float_as_uint(f);
    u += 0x7fff + ((u >> 16) & 1);          // RNE, finite inputs only
    return (unsigned short)(u >> 16);
}
__device__ __forceinline__ float b2f(unsigned short s) {
    return __uint_as_float(((unsigned)s) << 16);
}

// async global->LDS, 16B per lane; LDS dest is wave-uniform base (+lane*16 by HW)
__device__ __forceinline__ void gll16(const void* g, void* l) {
    __builtin_amdgcn_global_load_lds(
        (const __attribute__((address_space(1))) void*)g,
        (__attribute__((address_space(3))) void*)l,
        16, 0, 0);
}

// ---------------- f32 -> bf16 elementwise ----------------
__global__ void conv_bf16(const float* __restrict__ s, unsigned short* __restrict__ d, int n) {
    int i = (blockIdx.x * blockDim.x + threadIdx.x) * 4;
    if (i >= n) return;
    float4 v = *(const float4*)&s[i];
    ushort4 o;
    o.x = f2b(v.x); o.y = f2b(v.y); o.z = f2b(v.z); o.w = f2b(v.w);
    *(ushort4*)&d[i] = o;
}

// ---------------- transpose + convert: src [K][M] f32 -> dst [M][K] bf16 ----------------
__global__ void transpose_conv(const float* __restrict__ src, unsigned short* __restrict__ dst,
                               int K, int M) {
    __shared__ float tile[64][65];
    const int k0 = blockIdx.x * 64, m0 = blockIdx.y * 64;
    const int t  = threadIdx.x;
    const int tc = t & 15, tr = t >> 4;
    const float* s = src + (size_t)k0 * M + m0;
    #pragma unroll
    for (int r = tr; r < 64; r += 16) {
        float4 v = *(const float4*)&s[(size_t)r * M + tc * 4];
        tile[r][tc * 4 + 0] = v.x; tile[r][tc * 4 + 1] = v.y;
        tile[r][tc * 4 + 2] = v.z; tile[r][tc * 4 + 3] = v.w;
    }
    __syncthreads();
    unsigned short* d = dst + (size_t)m0 * K + k0;
    #pragma unroll
    for (int r = tr; r < 64; r += 16) {
        ushort4 o;
        o.x = f2b(tile[tc * 4 + 0][r]); o.y = f2b(tile[tc * 4 + 1][r]);
        o.z = f2b(tile[tc * 4 + 2][r]); o.w = f2b(tile[tc * 4 + 3][r]);
        *(ushort4*)&d[(size_t)r * K + tc * 4] = o;
    }
}

// ---------------- router: fp32 logits, softmax, first-max argmax, reg_loss ----------------
__global__ void router_kernel(const float* __restrict__ bb, const int* __restrict__ task,
                              const float* __restrict__ temb, const float* __restrict__ rm,
                              float* __restrict__ gval, int* __restrict__ gidx,
                              float* __restrict__ regout) {
    const int t = threadIdx.x, wave = t >> 6, lane = t & 63;
    const int n = blockIdx.x * 4 + wave;
    const int tk = task[n];
    float a0 = 0.f, a1 = 0.f, a2 = 0.f, a3 = 0.f;
    for (int i = lane; i < IN_DIM + 100; i += 64) {
        float x = (i < IN_DIM) ? bb[(size_t)n * IN_DIM + i] : temb[tk * 100 + (i - IN_DIM)];
        float4 r = *(const float4*)&rm[i * 4];
        a0 += x * r.x; a1 += x * r.y; a2 += x * r.z; a3 += x * r.w;
    }
    #pragma unroll
    for (int o = 32; o; o >>= 1) {
        a0 += __shfl_xor(a0, o); a1 += __shfl_xor(a1, o);
        a2 += __shfl_xor(a2, o); a3 += __shfl_xor(a3, o);
    }
    if (lane == 0) {
        float l[4] = {a0, a1, a2, a3};
        float mx = fmaxf(fmaxf(l[0], l[1]), fmaxf(l[2], l[3]));
        float ex[4], s = 0.f;
        #pragma unroll
        for (int j = 0; j < 4; j++) { ex[j] = expf(l[j] - mx); s += ex[j]; }
        int bi = 0; float bw = ex[0];
        #pragma unroll
        for (int j = 1; j < 4; j++) if (ex[j] > bw) { bw = ex[j]; bi = j; }
        float g = bw / s;
        gval[n] = g;
        gidx[n] = bi;
        regout[n] = -0.0025f * (logf(g + 1e-6f) + 3.0f * logf(1e-6f));
    }
}

// ---------------- per-expert compaction: list_e = {n : idx[n] >= e} ----------------
// one block (256 thr) per expert; stable ascending order; pads list to mult of 128 with 0
__global__ void compact_kernel(const int* __restrict__ gidx, int* __restrict__ list,
                               int* __restrict__ pos, int* __restrict__ cnt) {
    const int e = blockIdx.x;
    const int t = threadIdx.x, lane = t & 63, wave = t >> 6;
    __shared__ int wbase[4];
    __shared__ int running;
    if (t == 0) running = 0;
    __syncthreads();
    int* le = list + (size_t)e * N_SAMP;
    int* pe = pos + (size_t)e * N_SAMP;
    for (int base = 0; base < N_SAMP; base += 256) {
        const int n = base + t;
        const bool f = gidx[n] >= e;
        unsigned long long m = __ballot(f);
        int rank = __popcll(m & ((1ULL << lane) - 1ULL));
        if (lane == 0) wbase[wave] = __popcll(m);
        __syncthreads();
        int wb = 0;
        #pragma unroll
        for (int w = 0; w < 4; w++) if (w < wave) wb += wbase[w];
        int tot = wbase[0] + wbase[1] + wbase[2] + wbase[3];
        int o = running + wb + rank;
        if (f) { le[o] = n; pe[n] = o; }
        __syncthreads();
        if (t == 0) running += tot;
        __syncthreads();
    }
    const int c = running;
    if (t == 0) cnt[e] = c;
    const int padded = (c + 127) & ~127;
    for (int i = c + t; i < padded; i += 256) le[i] = 0;
}

// ---------------- bf16 MFMA GEMM: C[i][m] = relu(A[row(i),:] . BT[m,:] + bias[m]) ----------
// A: [*][K] bf16 gathered via rowlist (or identity), BT: [M][K] bf16
// 128x128 tile, BK=32, 4 waves; rows bounded by *cntp (C rows are compact indices)
__global__ __launch_bounds__(256) void gemm_bias_relu(
    const unsigned short* __restrict__ A, const unsigned short* __restrict__ BT,
    const float* __restrict__ bias, unsigned short* __restrict__ C,
    int K, int M, const int* __restrict__ rowlist, const int* __restrict__ cntp) {
    const int cnt = *cntp;
    const int n0 = blockIdx.y * 128;
    if (n0 >= cnt) return;
    __shared__ __attribute__((aligned(16))) unsigned short lA[128 * 32];
    __shared__ __attribute__((aligned(16))) unsigned short lB[128 * 32];
    const int t = threadIdx.x;
    const int m0 = blockIdx.x * 128;
    const unsigned short* Bb = BT + (size_t)m0 * K;
    const int wave = t >> 6, lane = t & 63;
    const int wr = wave >> 1, wc = wave & 1;
    const int lrow = lane & 15, kg = lane >> 4;

    // staging: chunk c covers 16B = row c>>2, 8-elem group c&3 of a [128][32] tile
    const int c0 = t, c1 = t + 256;
    const int r0 = c0 >> 2, o0 = (c0 & 3) * 8;
    const int r1 = c1 >> 2, o1 = (c1 & 3) * 8;
    const int gr0 = rowlist ? rowlist[n0 + r0] : (n0 + r0);
    const int gr1 = rowlist ? rowlist[n0 + r1] : (n0 + r1);
    const unsigned short* Ar0 = A + (size_t)gr0 * K + o0;
    const unsigned short* Ar1 = A + (size_t)gr1 * K + o1;
    unsigned short* lA0 = &lA[(size_t)wave * 512];
    unsigned short* lA1 = &lA[2048 + (size_t)wave * 512];
    unsigned short* lB0 = &lB[(size_t)wave * 512];
    unsigned short* lB1 = &lB[2048 + (size_t)wave * 512];

    f32x4 acc[4][4];
    #pragma unroll
    for (int i = 0; i < 4; i++)
        #pragma unroll
        for (int j = 0; j < 4; j++) acc[i][j] = (f32x4){0.f, 0.f, 0.f, 0.f};

    const int nk = K >> 5;
    for (int kt = 0; kt < nk; ++kt) {
        const unsigned short* Bk = Bb + kt * 32;
        gll16(Ar0 + kt * 32, lA0);
        gll16(Ar1 + kt * 32, lA1);
        gll16(Bk + (size_t)r0 * K + o0, lB0);
        gll16(Bk + (size_t)r1 * K + o1, lB1);
        __syncthreads();
        bf16x8 af[4], bfr[4];
        #pragma unroll
        for (int i = 0; i < 4; i++)
            af[i] = *(const bf16x8*)&lA[(wr * 64 + i * 16 + lrow) * 32 + kg * 8];
        #pragma unroll
        for (int j = 0; j < 4; j++)
            bfr[j] = *(const bf16x8*)&lB[(wc * 64 + j * 16 + lrow) * 32 + kg * 8];
        #pragma unroll
        for (int i = 0; i < 4; i++)
            #pragma unroll
            for (int j = 0; j < 4; j++)
                acc[i][j] = __builtin_amdgcn_mfma_f32_16x16x32_bf16(af[i], bfr[j], acc[i][j], 0, 0, 0);
        __syncthreads();
    }

    // epilogue: C/D layout col=lane&15, row=(lane>>4)*4+q  (m89-verified)
    float bv[4];
    #pragma unroll
    for (int j = 0; j < 4; j++)
        bv[j] = bias[m0 + wc * 64 + j * 16 + lrow];
    unsigned short* Cb = C + (size_t)n0 * M + m0;
    #pragma unroll
    for (int i = 0; i < 4; i++) {
        #pragma unroll
        for (int j = 0; j < 4; j++) {
            const int oc = wc * 64 + j * 16 + lrow;
            #pragma unroll
            for (int q = 0; q < 4; q++) {
                const int sr = wr * 64 + i * 16 + kg * 4 + q;
                if (n0 + sr < cnt) {
                    float x = acc[i][j][q] + bv[j];
                    x = fmaxf(x, 0.f);
                    Cb[(size_t)sr * M + oc] = f2b(x);
                }
            }
        }
    }
}

// ---------------- Gram-Schmidt + gather: one wave per sample (compact obf via pos) ------------
__global__ void gs_kernel(const unsigned short* __restrict__ eo, const float* __restrict__ gval,
                          const int* __restrict__ gidx, const int* __restrict__ pos,
                          float* __restrict__ dout) {
    const int t = threadIdx.x, wave = t >> 6, lane = t & 63;
    const int n = blockIdx.x * 4 + wave;
    const int idx = gidx[n];
    const float g = gval[n];

    float v[32], b0[32], b1[32], b2[32];

    auto loadv = [&](float* dst, int e) {
        const size_t row = pos[(size_t)e * N_SAMP + n];
        const unsigned short* p = eo + ((size_t)e * N_SAMP + row) * HID + lane * 8;
        #pragma unroll
        for (int c = 0; c < 4; c++) {
            uint4 u = *(const uint4*)(p + c * 512);
            const unsigned short* us = (const unsigned short*)&u;
            #pragma unroll
            for (int j = 0; j < 8; j++) dst[c * 8 + j] = b2f(us[j]);
        }
    };
    auto wdot = [&](const float* x, const float* y) -> float {
        float s = 0.f;
        #pragma unroll
        for (int k = 0; k < 32; k++) s += x[k] * y[k];
        #pragma unroll
        for (int o = 32; o; o >>= 1) s += __shfl_xor(s, o);
        return s;
    };
    auto storev = [&](const float* b) {
        float* o = dout + (size_t)n * HID + lane * 8;
        #pragma unroll
        for (int c = 0; c < 4; c++) {
            float4 x0, x1;
            x0.x = g * b[c * 8 + 0]; x0.y = g * b[c * 8 + 1];
            x0.z = g * b[c * 8 + 2]; x0.w = g * b[c * 8 + 3];
            x1.x = g * b[c * 8 + 4]; x1.y = g * b[c * 8 + 5];
            x1.z = g * b[c * 8 + 6]; x1.w = g * b[c * 8 + 7];
            *(float4*)(o + c * 512) = x0;
            *(float4*)(o + c * 512 + 4) = x1;
        }
    };

    loadv(v, 0);
    float inv = 1.f / sqrtf(wdot(v, v));
    #pragma unroll
    for (int k = 0; k < 32; k++) b0[k] = v[k] * inv;
    if (idx == 0) { storev(b0); return; }
    loadv(v, 1);
    {
        float cc0 = wdot(v, b0);
        #pragma unroll
        for (int k = 0; k < 32; k++) v[k] -= cc0 * b0[k];
        inv = 1.f / sqrtf(wdot(v, v));
        #pragma unroll
        for (int k = 0; k < 32; k++) b1[k] = v[k] * inv;
    }
    if (idx == 1) { storev(b1); return; }
    loadv(v, 2);
    {
        float cc0 = wdot(v, b0);
        float cc1 = wdot(v, b1);
        #pragma unroll
        for (int k = 0; k < 32; k++) v[k] -= cc0 * b0[k] + cc1 * b1[k];
        inv = 1.f / sqrtf(wdot(v, v));
        #pragma unroll
        for (int k = 0; k < 32; k++) b2[k] = v[k] * inv;
    }
    if (idx == 2) { storev(b2); return; }
    loadv(v, 3);
    {
        float cc0 = wdot(v, b0);
        float cc1 = wdot(v, b1);
        float cc2 = wdot(v, b2);
        #pragma unroll
        for (int k = 0; k < 32; k++) v[k] -= cc0 * b0[k] + cc1 * b1[k] + cc2 * b2[k];
        inv = 1.f / sqrtf(wdot(v, v));
        #pragma unroll
        for (int k = 0; k < 32; k++) v[k] *= inv;
    }
    storev(v);
}

extern "C" void kernel_launch(void* const* d_in, const int* in_sizes, int n_in,
                              void* d_out, int out_size, void* d_ws, size_t ws_size,
                              hipStream_t stream) {
    const float* bb   = (const float*)d_in[0];
    const int*   task = (const int*)d_in[1];
    const float* temb = (const float*)d_in[2];
    const float* rm   = (const float*)d_in[3];
    const float* W1   = (const float*)d_in[4];
    const float* b1   = (const float*)d_in[5];
    const float* W2   = (const float*)d_in[6];
    const float* b2   = (const float*)d_in[7];
    float* out = (float*)d_out;

    // workspace layout (bytes) -- total ~197.5 MB
    char* ws = (char*)d_ws;
    unsigned short* obf  = (unsigned short*)(ws + 0);           // 128 MB: [E][N][HID] bf16 (compact rows)
    unsigned short* Abf  = (unsigned short*)(ws + 134217728);   //  16 MB: [N][IN_DIM] bf16
    unsigned short* hbf  = (unsigned short*)(ws + 150994944);   //  32 MB: [N][HID] bf16 (per-expert, compact)
    unsigned short* W1T  = (unsigned short*)(ws + 184549376);   //   4 MB
    unsigned short* W2T  = (unsigned short*)(ws + 188743680);   //   8 MB
    float*          gv   = (float*)(ws + 197132288);            //  32 KB
    int*            gi   = (int*)(ws + 197165056);              //  32 KB
    int*            list = (int*)(ws + 197197824);              // 128 KB: [E][N]
    int*            pos  = (int*)(ws + 197328896);              // 128 KB: [E][N]
    int*            cnt  = (int*)(ws + 197459968);              //  16 B

    conv_bf16<<<(N_SAMP * IN_DIM) / 1024, 256, 0, stream>>>(bb, Abf, N_SAMP * IN_DIM);
    router_kernel<<<N_SAMP / 4, 256, 0, stream>>>(bb, task, temb, rm, gv, gi,
                                                  out + (size_t)N_SAMP * HID);
    compact_kernel<<<NE, 256, 0, stream>>>(gi, list, pos, cnt);

    for (int e = 0; e < NE; ++e) {
        transpose_conv<<<dim3(IN_DIM / 64, HID / 64), 256, 0, stream>>>(
            W1 + (size_t)e * IN_DIM * HID, W1T, IN_DIM, HID);
        gemm_bias_relu<<<dim3(HID / 128, N_SAMP / 128), 256, 0, stream>>>(
            Abf, W1T, b1 + (size_t)e * HID, hbf, IN_DIM, HID,
            list + (size_t)e * N_SAMP, cnt + e);
        transpose_conv<<<dim3(HID / 64, HID / 64), 256, 0, stream>>>(
            W2 + (size_t)e * HID * HID, W2T, HID, HID);
        gemm_bias_relu<<<dim3(HID / 128, N_SAMP / 128), 256, 0, stream>>>(
            hbf, W2T, b2 + (size_t)e * HID, obf + (size_t)e * N_SAMP * HID, HID, HID,
            nullptr, cnt + e);
    }

    gs_kernel<<<N_SAMP / 4, 256, 0, stream>>>(obf, gv, gi, pos, out);
}

// Round 4
// 612.773 us; speedup vs baseline: 1.2812x; 1.0660x over previous
//
#include <hip/hip_runtime.h>
#include <hip/hip_bf16.h>
#include <cstdint>

#define N_SAMP 8192
#define IN_DIM 1024
#define HID    2048
#define NE     4

typedef __attribute__((ext_vector_type(8))) __bf16 bf16x8;
typedef __attribute__((ext_vector_type(4))) float  f32x4;

__device__ __forceinline__ unsigned short f2b(float f) {
    unsigned u = __float_as_uint(f);
    u += 0x7fff + ((u >> 16) & 1);          // RNE, finite inputs only
    return (unsigned short)(u >> 16);
}
__device__ __forceinline__ float b2f(unsigned short s) {
    return __uint_as_float(((unsigned)s) << 16);
}

// async global->LDS, 16B per lane; LDS dest is wave-uniform base (+lane*16 by HW)
__device__ __forceinline__ void gll16(const void* g, void* l) {
    __builtin_amdgcn_global_load_lds(
        (const __attribute__((address_space(1))) void*)g,
        (__attribute__((address_space(3))) void*)l,
        16, 0, 0);
}

// ---------------- f32 -> bf16 elementwise ----------------
__global__ void conv_bf16(const float* __restrict__ s, unsigned short* __restrict__ d, int n) {
    int i = (blockIdx.x * blockDim.x + threadIdx.x) * 4;
    if (i >= n) return;
    float4 v = *(const float4*)&s[i];
    ushort4 o;
    o.x = f2b(v.x); o.y = f2b(v.y); o.z = f2b(v.z); o.w = f2b(v.w);
    *(ushort4*)&d[i] = o;
}

// ---------------- transpose + convert: src [K][M] f32 -> dst [M][K] bf16 ----------------
__global__ void transpose_conv(const float* __restrict__ src, unsigned short* __restrict__ dst,
                               int K, int M) {
    __shared__ float tile[64][65];
    const int k0 = blockIdx.x * 64, m0 = blockIdx.y * 64;
    const int t  = threadIdx.x;
    const int tc = t & 15, tr = t >> 4;
    const float* s = src + (size_t)k0 * M + m0;
    #pragma unroll
    for (int r = tr; r < 64; r += 16) {
        float4 v = *(const float4*)&s[(size_t)r * M + tc * 4];
        tile[r][tc * 4 + 0] = v.x; tile[r][tc * 4 + 1] = v.y;
        tile[r][tc * 4 + 2] = v.z; tile[r][tc * 4 + 3] = v.w;
    }
    __syncthreads();
    unsigned short* d = dst + (size_t)m0 * K + k0;
    #pragma unroll
    for (int r = tr; r < 64; r += 16) {
        ushort4 o;
        o.x = f2b(tile[tc * 4 + 0][r]); o.y = f2b(tile[tc * 4 + 1][r]);
        o.z = f2b(tile[tc * 4 + 2][r]); o.w = f2b(tile[tc * 4 + 3][r]);
        *(ushort4*)&d[(size_t)r * K + tc * 4] = o;
    }
}

// ---------------- router: fp32 logits, softmax, first-max argmax, reg_loss ----------------
__global__ void router_kernel(const float* __restrict__ bb, const int* __restrict__ task,
                              const float* __restrict__ temb, const float* __restrict__ rm,
                              float* __restrict__ gval, int* __restrict__ gidx,
                              float* __restrict__ regout) {
    const int t = threadIdx.x, wave = t >> 6, lane = t & 63;
    const int n = blockIdx.x * 4 + wave;
    const int tk = task[n];
    float a0 = 0.f, a1 = 0.f, a2 = 0.f, a3 = 0.f;
    for (int i = lane; i < IN_DIM + 100; i += 64) {
        float x = (i < IN_DIM) ? bb[(size_t)n * IN_DIM + i] : temb[tk * 100 + (i - IN_DIM)];
        float4 r = *(const float4*)&rm[i * 4];
        a0 += x * r.x; a1 += x * r.y; a2 += x * r.z; a3 += x * r.w;
    }
    #pragma unroll
    for (int o = 32; o; o >>= 1) {
        a0 += __shfl_xor(a0, o); a1 += __shfl_xor(a1, o);
        a2 += __shfl_xor(a2, o); a3 += __shfl_xor(a3, o);
    }
    if (lane == 0) {
        float l[4] = {a0, a1, a2, a3};
        float mx = fmaxf(fmaxf(l[0], l[1]), fmaxf(l[2], l[3]));
        float ex[4], s = 0.f;
        #pragma unroll
        for (int j = 0; j < 4; j++) { ex[j] = expf(l[j] - mx); s += ex[j]; }
        int bi = 0; float bw = ex[0];
        #pragma unroll
        for (int j = 1; j < 4; j++) if (ex[j] > bw) { bw = ex[j]; bi = j; }
        float g = bw / s;
        gval[n] = g;
        gidx[n] = bi;
        regout[n] = -0.0025f * (logf(g + 1e-6f) + 3.0f * logf(1e-6f));
    }
}

// ---------------- per-expert compaction: list_e = {n : idx[n] >= e} ----------------
__global__ void compact_kernel(const int* __restrict__ gidx, int* __restrict__ list,
                               int* __restrict__ pos, int* __restrict__ cnt) {
    const int e = blockIdx.x;
    const int t = threadIdx.x, lane = t & 63, wave = t >> 6;
    __shared__ int wbase[4];
    __shared__ int running;
    if (t == 0) running = 0;
    __syncthreads();
    int* le = list + (size_t)e * N_SAMP;
    int* pe = pos + (size_t)e * N_SAMP;
    for (int base = 0; base < N_SAMP; base += 256) {
        const int n = base + t;
        const bool f = gidx[n] >= e;
        unsigned long long m = __ballot(f);
        int rank = __popcll(m & ((1ULL << lane) - 1ULL));
        if (lane == 0) wbase[wave] = __popcll(m);
        __syncthreads();
        int wb = 0;
        #pragma unroll
        for (int w = 0; w < 4; w++) if (w < wave) wb += wbase[w];
        int tot = wbase[0] + wbase[1] + wbase[2] + wbase[3];
        int o = running + wb + rank;
        if (f) { le[o] = n; pe[n] = o; }
        __syncthreads();
        if (t == 0) running += tot;
        __syncthreads();
    }
    const int c = running;
    if (t == 0) cnt[e] = c;
    const int padded = (c + 127) & ~127;
    for (int i = c + t; i < padded; i += 256) le[i] = 0;
}

// ---------------- bf16 MFMA GEMM, prefetch double-buffered, XCD-ownership swizzle ----------
// C[i][m] = relu(A[row(i),:] . BT[m,:] + bias[m])
// A gathered via rowlist (or identity), BT: [M][K] bf16, 128x128 tile, BK=32, 4 waves.
// 1-D grid of (M/128)*(N_SAMP/128) blocks; XCD x owns m-blocks {2x,2x+1} (M/128 must be 16).
__global__ __launch_bounds__(256) void gemm_bias_relu(
    const unsigned short* __restrict__ A, const unsigned short* __restrict__ BT,
    const float* __restrict__ bias, unsigned short* __restrict__ C,
    int K, int M, const int* __restrict__ rowlist, const int* __restrict__ cntp) {
    // XCD-ownership decode: bid%8 = XCD (dispatch round-robins XCDs); each XCD
    // owns 2 m-columns, walks all n; adjacent l share the same A panel.
    const int bid = blockIdx.x;
    const int xcd = bid & 7, l = bid >> 3;
    const int mb = xcd * 2 + (l & 1);
    const int nb = l >> 1;
    const int cnt = *cntp;
    const int n0 = nb * 128;
    if (n0 >= cnt) return;
    const int m0 = mb * 128;

    __shared__ __attribute__((aligned(16))) unsigned short lA[2][128 * 32];
    __shared__ __attribute__((aligned(16))) unsigned short lB[2][128 * 32];
    const int t = threadIdx.x;
    const unsigned short* Bb = BT + (size_t)m0 * K;
    const int wave = t >> 6, lane = t & 63;
    const int wr = wave >> 1, wc = wave & 1;
    const int lrow = lane & 15, kg = lane >> 4;

    // staging: chunk c covers 16B = row c>>2, 8-elem group c&3 of a [128][32] tile
    const int c0 = t, c1 = t + 256;
    const int r0 = c0 >> 2, o0 = (c0 & 3) * 8;
    const int r1 = c1 >> 2, o1 = (c1 & 3) * 8;
    const int gr0 = rowlist ? rowlist[n0 + r0] : (n0 + r0);
    const int gr1 = rowlist ? rowlist[n0 + r1] : (n0 + r1);
    const unsigned short* Ar0 = A + (size_t)gr0 * K + o0;
    const unsigned short* Ar1 = A + (size_t)gr1 * K + o1;
    const unsigned short* Br0 = Bb + (size_t)r0 * K + o0;
    const unsigned short* Br1 = Bb + (size_t)r1 * K + o1;
    const int ldoff = wave * 512;   // per-wave contiguous 512-elem chunk

    f32x4 acc[4][4];
    #pragma unroll
    for (int i = 0; i < 4; i++)
        #pragma unroll
        for (int j = 0; j < 4; j++) acc[i][j] = (f32x4){0.f, 0.f, 0.f, 0.f};

    const int nk = K >> 5;
    // prologue: stage tile 0 into buffer 0
    gll16(Ar0, &lA[0][ldoff]);
    gll16(Ar1, &lA[0][2048 + ldoff]);
    gll16(Br0, &lB[0][ldoff]);
    gll16(Br1, &lB[0][2048 + ldoff]);
    __syncthreads();

    int cur = 0;
    for (int kt = 0; kt < nk; ++kt) {
        // prefetch tile kt+1 into the other buffer; latency hides under MFMA below
        if (kt + 1 < nk) {
            const int ko = (kt + 1) * 32;
            const int nx = cur ^ 1;
            gll16(Ar0 + ko, &lA[nx][ldoff]);
            gll16(Ar1 + ko, &lA[nx][2048 + ldoff]);
            gll16(Br0 + ko, &lB[nx][ldoff]);
            gll16(Br1 + ko, &lB[nx][2048 + ldoff]);
        }
        bf16x8 af[4], bfr[4];
        #pragma unroll
        for (int i = 0; i < 4; i++)
            af[i] = *(const bf16x8*)&lA[cur][(wr * 64 + i * 16 + lrow) * 32 + kg * 8];
        #pragma unroll
        for (int j = 0; j < 4; j++)
            bfr[j] = *(const bf16x8*)&lB[cur][(wc * 64 + j * 16 + lrow) * 32 + kg * 8];
        #pragma unroll
        for (int i = 0; i < 4; i++)
            #pragma unroll
            for (int j = 0; j < 4; j++)
                acc[i][j] = __builtin_amdgcn_mfma_f32_16x16x32_bf16(af[i], bfr[j], acc[i][j], 0, 0, 0);
        __syncthreads();   // drains vmcnt(0): prefetched tile ready; cur buffer free
        cur ^= 1;
    }

    // epilogue: C/D layout col=lane&15, row=(lane>>4)*4+q  (m89-verified)
    float bv[4];
    #pragma unroll
    for (int j = 0; j < 4; j++)
        bv[j] = bias[m0 + wc * 64 + j * 16 + lrow];
    unsigned short* Cb = C + (size_t)n0 * M + m0;
    #pragma unroll
    for (int i = 0; i < 4; i++) {
        #pragma unroll
        for (int j = 0; j < 4; j++) {
            const int oc = wc * 64 + j * 16 + lrow;
            #pragma unroll
            for (int q = 0; q < 4; q++) {
                const int sr = wr * 64 + i * 16 + kg * 4 + q;
                if (n0 + sr < cnt) {
                    float x = acc[i][j][q] + bv[j];
                    x = fmaxf(x, 0.f);
                    Cb[(size_t)sr * M + oc] = f2b(x);
                }
            }
        }
    }
}

// ---------------- Gram-Schmidt + gather: one wave per sample (compact obf via pos) ------------
__global__ void gs_kernel(const unsigned short* __restrict__ eo, const float* __restrict__ gval,
                          const int* __restrict__ gidx, const int* __restrict__ pos,
                          float* __restrict__ dout) {
    const int t = threadIdx.x, wave = t >> 6, lane = t & 63;
    const int n = blockIdx.x * 4 + wave;
    const int idx = gidx[n];
    const float g = gval[n];

    float v[32], b0[32], b1[32], b2[32];

    auto loadv = [&](float* dst, int e) {
        const size_t row = pos[(size_t)e * N_SAMP + n];
        const unsigned short* p = eo + ((size_t)e * N_SAMP + row) * HID + lane * 8;
        #pragma unroll
        for (int c = 0; c < 4; c++) {
            uint4 u = *(const uint4*)(p + c * 512);
            const unsigned short* us = (const unsigned short*)&u;
            #pragma unroll
            for (int j = 0; j < 8; j++) dst[c * 8 + j] = b2f(us[j]);
        }
    };
    auto wdot = [&](const float* x, const float* y) -> float {
        float s = 0.f;
        #pragma unroll
        for (int k = 0; k < 32; k++) s += x[k] * y[k];
        #pragma unroll
        for (int o = 32; o; o >>= 1) s += __shfl_xor(s, o);
        return s;
    };
    auto storev = [&](const float* b) {
        float* o = dout + (size_t)n * HID + lane * 8;
        #pragma unroll
        for (int c = 0; c < 4; c++) {
            float4 x0, x1;
            x0.x = g * b[c * 8 + 0]; x0.y = g * b[c * 8 + 1];
            x0.z = g * b[c * 8 + 2]; x0.w = g * b[c * 8 + 3];
            x1.x = g * b[c * 8 + 4]; x1.y = g * b[c * 8 + 5];
            x1.z = g * b[c * 8 + 6]; x1.w = g * b[c * 8 + 7];
            *(float4*)(o + c * 512) = x0;
            *(float4*)(o + c * 512 + 4) = x1;
        }
    };

    loadv(v, 0);
    float inv = 1.f / sqrtf(wdot(v, v));
    #pragma unroll
    for (int k = 0; k < 32; k++) b0[k] = v[k] * inv;
    if (idx == 0) { storev(b0); return; }
    loadv(v, 1);
    {
        float cc0 = wdot(v, b0);
        #pragma unroll
        for (int k = 0; k < 32; k++) v[k] -= cc0 * b0[k];
        inv = 1.f / sqrtf(wdot(v, v));
        #pragma unroll
        for (int k = 0; k < 32; k++) b1[k] = v[k] * inv;
    }
    if (idx == 1) { storev(b1); return; }
    loadv(v, 2);
    {
        float cc0 = wdot(v, b0);
        float cc1 = wdot(v, b1);
        #pragma unroll
        for (int k = 0; k < 32; k++) v[k] -= cc0 * b0[k] + cc1 * b1[k];
        inv = 1.f / sqrtf(wdot(v, v));
        #pragma unroll
        for (int k = 0; k < 32; k++) b2[k] = v[k] * inv;
    }
    if (idx == 2) { storev(b2); return; }
    loadv(v, 3);
    {
        float cc0 = wdot(v, b0);
        float cc1 = wdot(v, b1);
        float cc2 = wdot(v, b2);
        #pragma unroll
        for (int k = 0; k < 32; k++) v[k] -= cc0 * b0[k] + cc1 * b1[k] + cc2 * b2[k];
        inv = 1.f / sqrtf(wdot(v, v));
        #pragma unroll
        for (int k = 0; k < 32; k++) v[k] *= inv;
    }
    storev(v);
}

extern "C" void kernel_launch(void* const* d_in, const int* in_sizes, int n_in,
                              void* d_out, int out_size, void* d_ws, size_t ws_size,
                              hipStream_t stream) {
    const float* bb   = (const float*)d_in[0];
    const int*   task = (const int*)d_in[1];
    const float* temb = (const float*)d_in[2];
    const float* rm   = (const float*)d_in[3];
    const float* W1   = (const float*)d_in[4];
    const float* b1   = (const float*)d_in[5];
    const float* W2   = (const float*)d_in[6];
    const float* b2   = (const float*)d_in[7];
    float* out = (float*)d_out;

    // workspace layout (bytes) -- total ~197.5 MB (proven safe in round 2)
    char* ws = (char*)d_ws;
    unsigned short* obf  = (unsigned short*)(ws + 0);           // 128 MB: [E][N][HID] bf16 (compact rows)
    unsigned short* Abf  = (unsigned short*)(ws + 134217728);   //  16 MB: [N][IN_DIM] bf16
    unsigned short* hbf  = (unsigned short*)(ws + 150994944);   //  32 MB: [N][HID] bf16 (per-expert, compact)
    unsigned short* W1T  = (unsigned short*)(ws + 184549376);   //   4 MB
    unsigned short* W2T  = (unsigned short*)(ws + 188743680);   //   8 MB
    float*          gv   = (float*)(ws + 197132288);            //  32 KB
    int*            gi   = (int*)(ws + 197165056);              //  32 KB
    int*            list = (int*)(ws + 197197824);              // 128 KB: [E][N]
    int*            pos  = (int*)(ws + 197328896);              // 128 KB: [E][N]
    int*            cnt  = (int*)(ws + 197459968);              //  16 B

    conv_bf16<<<(N_SAMP * IN_DIM) / 1024, 256, 0, stream>>>(bb, Abf, N_SAMP * IN_DIM);
    router_kernel<<<N_SAMP / 4, 256, 0, stream>>>(bb, task, temb, rm, gv, gi,
                                                  out + (size_t)N_SAMP * HID);
    compact_kernel<<<NE, 256, 0, stream>>>(gi, list, pos, cnt);

    const int gemm_blocks = (HID / 128) * (N_SAMP / 128);   // 16 * 64 = 1024
    for (int e = 0; e < NE; ++e) {
        transpose_conv<<<dim3(IN_DIM / 64, HID / 64), 256, 0, stream>>>(
            W1 + (size_t)e * IN_DIM * HID, W1T, IN_DIM, HID);
        gemm_bias_relu<<<gemm_blocks, 256, 0, stream>>>(
            Abf, W1T, b1 + (size_t)e * HID, hbf, IN_DIM, HID,
            list + (size_t)e * N_SAMP, cnt + e);
        transpose_conv<<<dim3(HID / 64, HID / 64), 256, 0, stream>>>(
            W2 + (size_t)e * HID * HID, W2T, HID, HID);
        gemm_bias_relu<<<gemm_blocks, 256, 0, stream>>>(
            hbf, W2T, b2 + (size_t)e * HID, obf + (size_t)e * N_SAMP * HID, HID, HID,
            nullptr, cnt + e);
    }

    gs_kernel<<<N_SAMP / 4, 256, 0, stream>>>(obf, gv, gi, pos, out);
}